// Round 1
// baseline (83.489 us; speedup 1.0000x reference)
//
#include <hip/hip_runtime.h>
#include <math.h>

// SiameseLDDTLoss on MI355X (gfx950).
// Shapes fixed by the reference: B=8, L=2048, D=128, A=1024.
// Strategy: never l2-normalize the full [B,L,D] tensors — only the gathered
// rows matter. One 64-lane wave per alignment pair: gather 2 rows (float2 per
// lane), shuffle-reduce dot/|v1|^2/|v2|^2, write per-pair squared error to ws.
// Deterministic final reduction in a single block (no atomics, every ws slot
// written each call -> safe under 0xAA re-poison).

constexpr int B_ = 8;
constexpr int L_ = 2048;
constexpr int D_ = 128;
constexpr int A_ = 1024;
constexpr int NPAIR = B_ * A_;   // 8192
constexpr float ALPHA = 0.7f;
constexpr float BETA  = 0.3f;
constexpr float EPS   = 1e-12f;

__device__ __forceinline__ float wave_reduce_sum(float v) {
    // full 64-lane butterfly
    #pragma unroll
    for (int m = 32; m >= 1; m >>= 1) v += __shfl_xor(v, m, 64);
    return v;
}

// 4 waves / block, one alignment pair per wave.
__global__ void residue_kernel(const float* __restrict__ e1,
                               const float* __restrict__ e2,
                               const float* __restrict__ lddt,
                               const int*   __restrict__ align,
                               float*       __restrict__ ws) {
    const int wave = (blockIdx.x * blockDim.x + threadIdx.x) >> 6;  // == pair id
    const int lane = threadIdx.x & 63;
    if (wave >= NPAIR) return;
    const int b = wave >> 10;              // wave / A_
    const int i = align[wave * 2 + 0];
    const int j = align[wave * 2 + 1];

    const float2* r1 = reinterpret_cast<const float2*>(e1 + (size_t)(b * L_ + i) * D_);
    const float2* r2 = reinterpret_cast<const float2*>(e2 + (size_t)(b * L_ + j) * D_);
    const float2 a1 = r1[lane];
    const float2 a2 = r2[lane];

    float dot = a1.x * a2.x + a1.y * a2.y;
    float n1  = a1.x * a1.x + a1.y * a1.y;
    float n2  = a2.x * a2.x + a2.y * a2.y;
    dot = wave_reduce_sum(dot);
    n1  = wave_reduce_sum(n1);
    n2  = wave_reduce_sum(n2);

    if (lane == 0) {
        const float sim = dot / (fmaxf(sqrtf(n1), EPS) * fmaxf(sqrtf(n2), EPS));
        const float d   = sim - lddt[b * L_ + i];
        ws[wave] = d * d;
    }
}

// 8 waves (one block of 512), one batch row per wave.
__global__ void global_kernel(const float* __restrict__ g1,
                              const float* __restrict__ g2,
                              float*       __restrict__ ws) {
    const int wave = threadIdx.x >> 6;    // 0..7 == b
    const int lane = threadIdx.x & 63;

    const float2* r1 = reinterpret_cast<const float2*>(g1 + (size_t)wave * D_);
    const float2* r2 = reinterpret_cast<const float2*>(g2 + (size_t)wave * D_);
    const float2 a1 = r1[lane];
    const float2 a2 = r2[lane];

    float dot = a1.x * a2.x + a1.y * a2.y;
    float n1  = a1.x * a1.x + a1.y * a1.y;
    float n2  = a2.x * a2.x + a2.y * a2.y;
    dot = wave_reduce_sum(dot);
    n1  = wave_reduce_sum(n1);
    n2  = wave_reduce_sum(n2);

    if (lane == 0) {
        const float cosv = dot / (fmaxf(sqrtf(n1), EPS) * fmaxf(sqrtf(n2), EPS));
        const float d    = cosv - 0.8f;
        ws[NPAIR + wave] = d * d;
    }
}

// single block, 256 threads: reduce 8192 residue terms + 8 global terms,
// emit (total, residue, global).
__global__ void finalize_kernel(const float* __restrict__ ws,
                                float*       __restrict__ out) {
    __shared__ float s_res[4];
    __shared__ float s_glob[4];
    const int tid  = threadIdx.x;
    const int wave = tid >> 6;
    const int lane = tid & 63;

    float r = 0.0f;
    for (int idx = tid; idx < NPAIR; idx += 256) r += ws[idx];
    float g = (tid < B_) ? ws[NPAIR + tid] : 0.0f;

    r = wave_reduce_sum(r);
    g = wave_reduce_sum(g);
    if (lane == 0) { s_res[wave] = r; s_glob[wave] = g; }
    __syncthreads();

    if (tid == 0) {
        const float res  = s_res[0] + s_res[1] + s_res[2] + s_res[3];
        const float glob = s_glob[0] + s_glob[1] + s_glob[2] + s_glob[3];
        const float residue_loss = res  / (float)NPAIR;
        const float global_loss  = glob / (float)B_;
        out[0] = ALPHA * residue_loss + BETA * global_loss;  // total_loss
        out[1] = residue_loss;
        out[2] = global_loss;
    }
}

extern "C" void kernel_launch(void* const* d_in, const int* in_sizes, int n_in,
                              void* d_out, int out_size, void* d_ws, size_t ws_size,
                              hipStream_t stream) {
    const float* e1    = (const float*)d_in[0];  // new_emb1 [8,2048,128]
    const float* e2    = (const float*)d_in[1];  // new_emb2 [8,2048,128]
    const float* g1    = (const float*)d_in[2];  // global_emb1 [8,128]
    const float* g2    = (const float*)d_in[3];  // global_emb2 [8,128]
    const float* lddt  = (const float*)d_in[4];  // lddt_scores [8,2048]
    // d_in[5] alignment_mask: unused by the reference math
    const int*   align = (const int*)d_in[6];    // alignment [8,1024,2]
    float* ws  = (float*)d_ws;                   // [8192 + 8] floats
    float* out = (float*)d_out;                  // 3 floats

    // 8192 pairs, 4 waves/block -> 2048 blocks
    residue_kernel<<<NPAIR / 4, 256, 0, stream>>>(e1, e2, lddt, align, ws);
    global_kernel<<<1, 512, 0, stream>>>(g1, g2, ws);
    finalize_kernel<<<1, 256, 0, stream>>>(ws, out);
}